// Round 1
// baseline (4115.361 us; speedup 1.0000x reference)
//
#include <hip/hip_runtime.h>

#define B_ 16
#define N_ 4096
#define M_ 1024
#define S_ 32
#define IN_ 64
#define C0IN 67
#define C0 64
#define C1 64
#define C2 128
#define NTOT (B_*M_*S_)
#define R2 0.04f
#define CAP 1024

// ---------------- FPS ----------------
// One 1024-thread block (16 waves) per batch. 4 points/lane register-resident
// (16 VGPRs). Per iteration: per-lane dist update + 64-lane butterfly argmax +
// cross-wave reduce via double-buffered 16-entry LDS array (ONE barrier/iter).
// Tie-break: (dist desc, idx asc) lexicographic == jnp.argmax first-index.
__global__ __launch_bounds__(1024, 1) void fps_kernel(const float* __restrict__ xyz,
                                                      int* __restrict__ fps_idx,
                                                      float* __restrict__ out_xyz) {
#pragma clang fp contract(off)
    __shared__ float px[N_], py[N_], pz[N_];
    __shared__ float rv[2][16];
    __shared__ int   ri[2][16];
    int b = blockIdx.x, t = threadIdx.x;
    const float* xb = xyz + (size_t)b * N_ * 3;
    for (int i = t; i < N_; i += 1024) {
        px[i] = xb[i*3+0]; py[i] = xb[i*3+1]; pz[i] = xb[i*3+2];
    }
    __syncthreads();
    float lx[4], ly[4], lz[4], dl[4];
#pragma unroll
    for (int j = 0; j < 4; j++) {
        int i = (j << 10) + t;
        lx[j] = px[i]; ly[j] = py[i]; lz[j] = pz[i];
        dl[j] = __builtin_inff();
    }
    int wid = t >> 6;
    int lane = t & 63;
    int cur = 0;
    for (int k = 0; k < M_; k++) {
        float cx = px[cur], cy = py[cur], cz = pz[cur];
        if (t == 0) {
            fps_idx[b*M_ + k] = cur;
            out_xyz[(b*M_ + k)*3 + 0] = cx;
            out_xyz[(b*M_ + k)*3 + 1] = cy;
            out_xyz[(b*M_ + k)*3 + 2] = cz;
        }
        float bv = -1.0f; int bi = 0x7fffffff;
#pragma unroll
        for (int j = 0; j < 4; j++) {
            float dx = lx[j] - cx, dy = ly[j] - cy, dz = lz[j] - cz;
            float t0 = dx*dx, t1 = dy*dy, t2 = dz*dz;
            float d = (t0 + t1) + t2;
            float od = dl[j];
            float nd = d < od ? d : od;
            dl[j] = nd;
            if (nd > bv) { bv = nd; bi = (j << 10) + t; }  // strict > keeps smaller idx per lane
        }
        // 64-lane butterfly argmax, ties -> smaller global index; all lanes converge
        for (int off = 32; off >= 1; off >>= 1) {
            float ov = __shfl_xor(bv, off, 64);
            int   oi = __shfl_xor(bi, off, 64);
            if (ov > bv || (ov == bv && oi < bi)) { bv = ov; bi = oi; }
        }
        int p = k & 1;
        if (lane == 0) { rv[p][wid] = bv; ri[p][wid] = bi; }
        __syncthreads();
        // all threads redundantly reduce 16 wave-winners (LDS broadcast reads)
        float gv = rv[p][0]; int gi = ri[p][0];
#pragma unroll
        for (int j = 1; j < 16; j++) {
            float ov = rv[p][j]; int oi = ri[p][j];
            if (ov > gv || (ov == gv && oi < gi)) { gv = ov; gi = oi; }
        }
        cur = gi;
        // NOTE: no second barrier needed: iter k+1 writes buffer (k+1)&1, whose
        // previous readers (iter k-1) are separated by iter k's barrier.
    }
}

// ---------------- Ball query ----------------
// One block per center, single pass: collect candidates (d<=r^2) into LDS via
// atomic, track global argmin. Then rank candidates by (d, idx) lexicographic
// (== stable argsort ascending); slots >= count get the nearest index.
__global__ __launch_bounds__(256) void ballq_kernel(const float* __restrict__ xyz,
                                                    const int* __restrict__ fps_idx,
                                                    int* __restrict__ ball_idx) {
#pragma clang fp contract(off)
    __shared__ float cd[CAP];
    __shared__ int   ci[CAP];
    __shared__ int   cnt;
    __shared__ float rv[4];
    __shared__ int   ri[4];
    __shared__ int   slots[33];  // [0..31] ranked candidates, [32] global argmin
    int blk = blockIdx.x;
    int b = blk >> 10, m = blk & (M_ - 1);
    int t = threadIdx.x;
    if (t == 0) cnt = 0;
    __syncthreads();
    const float* xb = xyz + (size_t)b * N_ * 3;
    int cidx = fps_idx[b*M_ + m];
    float cx = xb[cidx*3+0], cy = xb[cidx*3+1], cz = xb[cidx*3+2];
    float bv = 3.4e38f; int bi = 0x7fffffff;
    for (int i = t; i < N_; i += 256) {
        float dx = xb[i*3+0] - cx, dy = xb[i*3+1] - cy, dz = xb[i*3+2] - cz;
        float t0 = dx*dx, t1 = dy*dy, t2 = dz*dz;
        float d = (t0 + t1) + t2;
        if (d < bv || (d == bv && i < bi)) { bv = d; bi = i; }
        if (d <= R2) {
            int p = atomicAdd(&cnt, 1);
            if (p < CAP) { cd[p] = d; ci[p] = i; }
        }
    }
    // global argmin reduce (needed when no candidate within radius)
    for (int off = 32; off >= 1; off >>= 1) {
        float ov = __shfl_xor(bv, off, 64);
        int   oi = __shfl_xor(bi, off, 64);
        if (ov < bv || (ov == bv && oi < bi)) { bv = ov; bi = oi; }
    }
    int w = t >> 6;
    if ((t & 63) == 0) { rv[w] = bv; ri[w] = bi; }
    __syncthreads();
    int n = cnt < CAP ? cnt : CAP;
    // rank each candidate; rank < 32 writes its output slot
    for (int j = t; j < n; j += 256) {
        float dj = cd[j]; int ij = ci[j];
        int rank = 0;
        for (int k = 0; k < n; k++) {
            float dk = cd[k]; int ik = ci[k];
            rank += (dk < dj) || (dk == dj && ik < ij);
        }
        if (rank < S_) slots[rank] = ij;
    }
    if (t == 0) {
        float v = rv[0]; int ix = ri[0];
        for (int j = 1; j < 4; j++)
            if (rv[j] < v || (rv[j] == v && ri[j] < ix)) { v = rv[j]; ix = ri[j]; }
        slots[32] = ix;
    }
    __syncthreads();
    if (t < S_) {
        int nearest = (n > 0) ? slots[0] : slots[32];
        int ix = (t < n) ? slots[t] : nearest;
        ball_idx[(size_t)(b*M_ + m)*S_ + t] = ix;
    }
}

// ---------------- MLP chain ----------------
// One block per center; whole chain in LDS. MODE: 0=stats L0, 1=stats L1,
// 2=stats L2, 3=final (normalize L2 + relu + max over samples -> out).
// stats layout: [sum0(64) sq0(64) sum1(64) sq1(64) sum2(128) sq2(128)]
// coef  layout: [a0(64) c0(64) a1(64) c1(64) a2(128) c2(128)], y_n = y*a + c
template<int MODE>
__global__ __launch_bounds__(256) void mlp_kernel(
    const float* __restrict__ xyz, const float* __restrict__ feat,
    const int* __restrict__ fps_idx, const int* __restrict__ ball_idx,
    const float* __restrict__ w0, const float* __restrict__ b0,
    const float* __restrict__ w1, const float* __restrict__ b1,
    const float* __restrict__ w2, const float* __restrict__ b2,
    const float* __restrict__ coef, float* __restrict__ stats,
    float* __restrict__ out_feat) {
    __shared__ float xs[S_*C0IN];
    __shared__ float y0s[S_*C0];
    __shared__ float y1s[S_*C1];
    __shared__ float red[256];
    __shared__ float red2[256];
    __shared__ int idxs[S_];
    int blk = blockIdx.x;
    int b = blk >> 10, m = blk & (M_ - 1);
    int t = threadIdx.x;
    const float* xb = xyz + (size_t)b * N_ * 3;
    int cidx = fps_idx[b*M_ + m];
    float cx = xb[cidx*3+0], cy = xb[cidx*3+1], cz = xb[cidx*3+2];
    if (t < S_) idxs[t] = ball_idx[(size_t)(b*M_ + m)*S_ + t];
    __syncthreads();
    // gather x = [grouped_xyz(3) | grouped_feat(64)]
    for (int i = t; i < S_*C0IN; i += 256) {
        int s = i / C0IN, c = i - s * C0IN;
        int p = idxs[s];
        float v;
        if (c == 0)      v = xb[p*3+0] - cx;
        else if (c == 1) v = xb[p*3+1] - cy;
        else if (c == 2) v = xb[p*3+2] - cz;
        else             v = feat[((size_t)b*N_ + p)*IN_ + (c - 3)];
        xs[i] = v;
    }
    __syncthreads();
    // ---- layer 0: 67 -> 64
    {
        float lsum = 0.f, lsq = 0.f;
        int d = t & 63;
        for (int o = t; o < S_*C0; o += 256) {
            int s = o >> 6;
            float acc = b0[d];
            const float* wr = w0 + d * C0IN;
            const float* xr = xs + s * C0IN;
            for (int c = 0; c < C0IN; c++) acc += xr[c] * wr[c];
            if (MODE == 0) { lsum += acc; lsq += acc * acc; }
            else {
                float v = acc * coef[d] + coef[64 + d];
                y0s[s*C0 + d] = v > 0.f ? v : 0.f;
            }
        }
        if (MODE == 0) {
            red[t] = lsum; red2[t] = lsq;
            __syncthreads();
            if (t < 64) {
                atomicAdd(&stats[t],      red[t]  + red[t+64]  + red[t+128]  + red[t+192]);
                atomicAdd(&stats[64 + t], red2[t] + red2[t+64] + red2[t+128] + red2[t+192]);
            }
            return;
        }
    }
    __syncthreads();
    // ---- layer 1: 64 -> 64
    {
        float lsum = 0.f, lsq = 0.f;
        int d = t & 63;
        for (int o = t; o < S_*C1; o += 256) {
            int s = o >> 6;
            float acc = b1[d];
            const float* wr = w1 + d * C0;
            const float* yr = y0s + s * C0;
            for (int c = 0; c < C0; c++) acc += yr[c] * wr[c];
            if (MODE == 1) { lsum += acc; lsq += acc * acc; }
            else {
                float v = acc * coef[128 + d] + coef[192 + d];
                y1s[s*C1 + d] = v > 0.f ? v : 0.f;
            }
        }
        if (MODE == 1) {
            red[t] = lsum; red2[t] = lsq;
            __syncthreads();
            if (t < 64) {
                atomicAdd(&stats[128 + t], red[t]  + red[t+64]  + red[t+128]  + red[t+192]);
                atomicAdd(&stats[192 + t], red2[t] + red2[t+64] + red2[t+128] + red2[t+192]);
            }
            return;
        }
    }
    __syncthreads();
    // ---- layer 2: 64 -> 128
    {
        int d = t & 127;
        float lsum = 0.f, lsq = 0.f, lmax = -3.4e38f;
        for (int o = t; o < S_*C2; o += 256) {
            int s = o >> 7;
            float acc = b2[d];
            const float* wr = w2 + d * C1;
            const float* yr = y1s + s * C1;
            for (int c = 0; c < C1; c++) acc += yr[c] * wr[c];
            if (MODE == 2) { lsum += acc; lsq += acc * acc; }
            else {
                float v = acc * coef[256 + d] + coef[384 + d];
                v = v > 0.f ? v : 0.f;
                lmax = v > lmax ? v : lmax;
            }
        }
        if (MODE == 2) {
            red[t] = lsum; red2[t] = lsq;
            __syncthreads();
            if (t < 128) {
                atomicAdd(&stats[256 + t], red[t]  + red[t+128]);
                atomicAdd(&stats[384 + t], red2[t] + red2[t+128]);
            }
            return;
        }
        red[t] = lmax;
        __syncthreads();
        if (t < 128) {
            float v = red[t] > red[t+128] ? red[t] : red[t+128];
            out_feat[(size_t)(b*M_ + m)*C2 + t] = v;
        }
    }
}

// mean/var -> affine coefs: y_n = y*a + c
__global__ void finalize_kernel(const float* __restrict__ stats,
                                const float* __restrict__ gamma,
                                const float* __restrict__ beta,
                                float* __restrict__ coef, int C) {
    int t = threadIdx.x;
    if (t < C) {
        float inv_n = 1.0f / (float)NTOT;
        float mean = stats[t] * inv_n;
        float var = stats[C + t] * inv_n - mean * mean;
        float rstd = 1.0f / sqrtf(var + 1e-5f);
        float a = gamma[t] * rstd;
        coef[t] = a;
        coef[C + t] = beta[t] - mean * a;
    }
}

extern "C" void kernel_launch(void* const* d_in, const int* in_sizes, int n_in,
                              void* d_out, int out_size, void* d_ws, size_t ws_size,
                              hipStream_t stream) {
    const float* xyz  = (const float*)d_in[0];
    const float* feat = (const float*)d_in[1];
    const float* w0 = (const float*)d_in[2];  const float* b0 = (const float*)d_in[3];
    const float* g0 = (const float*)d_in[4];  const float* be0 = (const float*)d_in[5];
    const float* w1 = (const float*)d_in[6];  const float* b1 = (const float*)d_in[7];
    const float* g1 = (const float*)d_in[8];  const float* be1 = (const float*)d_in[9];
    const float* w2 = (const float*)d_in[10]; const float* b2 = (const float*)d_in[11];
    const float* g2 = (const float*)d_in[12]; const float* be2 = (const float*)d_in[13];
    float* out_xyz  = (float*)d_out;
    float* out_feat = out_xyz + B_*M_*3;

    int* fps_i  = (int*)d_ws;                                   // 16384 ints
    int* ball_i = (int*)((char*)d_ws + 65536);                  // 524288 ints
    float* stats = (float*)((char*)d_ws + 65536 + 2097152);     // 512 floats
    float* coef  = stats + 512;                                 // 512 floats

    hipMemsetAsync(stats, 0, 512 * sizeof(float), stream);
    fps_kernel<<<B_, 1024, 0, stream>>>(xyz, fps_i, out_xyz);
    ballq_kernel<<<B_*M_, 256, 0, stream>>>(xyz, fps_i, ball_i);
    mlp_kernel<0><<<B_*M_, 256, 0, stream>>>(xyz, feat, fps_i, ball_i,
        w0, b0, w1, b1, w2, b2, coef, stats, out_feat);
    finalize_kernel<<<1, 128, 0, stream>>>(stats, g0, be0, coef, 64);
    mlp_kernel<1><<<B_*M_, 256, 0, stream>>>(xyz, feat, fps_i, ball_i,
        w0, b0, w1, b1, w2, b2, coef, stats, out_feat);
    finalize_kernel<<<1, 128, 0, stream>>>(stats + 128, g1, be1, coef + 128, 64);
    mlp_kernel<2><<<B_*M_, 256, 0, stream>>>(xyz, feat, fps_i, ball_i,
        w0, b0, w1, b1, w2, b2, coef, stats, out_feat);
    finalize_kernel<<<1, 128, 0, stream>>>(stats + 256, g2, be2, coef + 256, 128);
    mlp_kernel<3><<<B_*M_, 256, 0, stream>>>(xyz, feat, fps_i, ball_i,
        w0, b0, w1, b1, w2, b2, coef, stats, out_feat);
}

// Round 2
// 2807.256 us; speedup vs baseline: 1.4660x; 1.4660x over previous
//
#include <hip/hip_runtime.h>

#define B_ 16
#define N_ 4096
#define M_ 1024
#define S_ 32
#define IN_ 64
#define C0IN 67
#define C0 64
#define C1 64
#define C2 128
#define NTOT (B_*M_*S_)
#define R2 0.04f
#define CAP 1024

#define FPS_T 256
#define FPS_PTS (N_ / FPS_T)   // 16 points per lane

// DPP wave-64 reductions at VALU speed (no DS ops).
// row_shr:1/2/4/8 prefix within 16-lane rows, then row_bcast:15/31 -> lane 63.
// bound_ctrl=false + old=v : invalid lanes keep old value (identity for max/min).
#define DPP_F32_MAX(v, ctrl) \
    v = fmaxf(v, __int_as_float(__builtin_amdgcn_update_dpp( \
            __float_as_int(v), __float_as_int(v), ctrl, 0xF, 0xF, false)))
#define DPP_S32_MIN(v, ctrl) \
    { int _o = __builtin_amdgcn_update_dpp(v, v, ctrl, 0xF, 0xF, false); \
      v = _o < v ? _o : v; }

// ---------------- FPS ----------------
// One 256-thread block (4 waves, 1/SIMD) per batch. 16 points/lane pinned in
// VGPRs via asm (defeats LDS-rematerialization seen as VGPR_Count=20).
// Per iteration: per-lane dist update -> DPP value-max reduce -> readlane ->
// DPP idx-min reduce among max-holders -> cross-wave reduce via double-buffered
// 4-entry LDS array (ONE barrier/iter). No global stores in the loop (sel[] in
// LDS, dumped in epilogue) so the barrier needs no vmcnt drain.
// Tie-break: (dist desc, idx asc) == jnp.argmax first-index semantics.
__global__ __launch_bounds__(FPS_T, 1) void fps_kernel(const float* __restrict__ xyz,
                                                       int* __restrict__ fps_idx,
                                                       float* __restrict__ out_xyz) {
#pragma clang fp contract(off)
    __shared__ float px[N_], py[N_], pz[N_];
    __shared__ int   sel[M_];
    __shared__ float rv[2][4];
    __shared__ int   ri[2][4];
    int b = blockIdx.x, t = threadIdx.x;
    const float* xb = xyz + (size_t)b * N_ * 3;
    for (int i = t; i < N_; i += FPS_T) {
        px[i] = xb[i*3+0]; py[i] = xb[i*3+1]; pz[i] = xb[i*3+2];
    }
    __syncthreads();
    float lx[FPS_PTS], ly[FPS_PTS], lz[FPS_PTS], dl[FPS_PTS];
#pragma unroll
    for (int j = 0; j < FPS_PTS; j++) {
        int i = j * FPS_T + t;
        lx[j] = px[i]; ly[j] = py[i]; lz[j] = pz[i];
        dl[j] = __builtin_inff();
        // pin coords in VGPRs: opaque to compiler -> cannot re-load from LDS
        asm volatile("" : "+v"(lx[j]), "+v"(ly[j]), "+v"(lz[j]));
    }
    int wid = t >> 6, lane = t & 63;
    int cur = 0;
    for (int k = 0; k < M_; k++) {
        float cx = px[cur], cy = py[cur], cz = pz[cur];
        if (t == 0) sel[k] = cur;
        float bv = -1.0f; int bi = 0x7fffffff;
#pragma unroll
        for (int j = 0; j < FPS_PTS; j++) {
            float dx = lx[j] - cx, dy = ly[j] - cy, dz = lz[j] - cz;
            float t0 = dx*dx, t1 = dy*dy, t2 = dz*dz;
            float d = (t0 + t1) + t2;
            float od = dl[j];
            float nd = d < od ? d : od;
            dl[j] = nd;
            if (nd > bv) { bv = nd; bi = j * FPS_T + t; }  // strict > keeps smallest idx per lane
        }
        // ---- wave argmax, VALU-only ----
        // 1) value max -> lane 63 -> SGPR broadcast
        float m = bv;
        DPP_F32_MAX(m, 0x111);  // row_shr:1
        DPP_F32_MAX(m, 0x112);  // row_shr:2
        DPP_F32_MAX(m, 0x114);  // row_shr:4
        DPP_F32_MAX(m, 0x118);  // row_shr:8
        DPP_F32_MAX(m, 0x142);  // row_bcast:15
        DPP_F32_MAX(m, 0x143);  // row_bcast:31
        float wmax = __int_as_float(__builtin_amdgcn_readlane(__float_as_int(m), 63));
        // 2) min global index among lanes holding the max (fmax returns inputs
        //    bit-exact; dists are non-negative -> equality is safe)
        int cand = (bv == wmax) ? bi : 0x7fffffff;
        DPP_S32_MIN(cand, 0x111);
        DPP_S32_MIN(cand, 0x112);
        DPP_S32_MIN(cand, 0x114);
        DPP_S32_MIN(cand, 0x118);
        DPP_S32_MIN(cand, 0x142);
        DPP_S32_MIN(cand, 0x143);
        int widx = __builtin_amdgcn_readlane(cand, 63);
        // ---- cross-wave reduce (4 entries), double-buffered, ONE barrier ----
        int p = k & 1;
        if (lane == 0) { rv[p][wid] = wmax; ri[p][wid] = widx; }
        __syncthreads();
        float gv = rv[p][0]; int gi = ri[p][0];
#pragma unroll
        for (int j = 1; j < 4; j++) {
            float ov = rv[p][j]; int oi = ri[p][j];
            if (ov > gv || (ov == gv && oi < gi)) { gv = ov; gi = oi; }
        }
        cur = gi;
        // no 2nd barrier: iter k+1 writes buffer (k+1)&1, whose previous
        // readers (iter k-1) are separated by iter k's barrier.
    }
    __syncthreads();
    // epilogue: dump selected indices + coords (parallel, coalesced-ish)
    for (int i = t; i < M_; i += FPS_T) {
        int ix = sel[i];
        fps_idx[b*M_ + i] = ix;
        out_xyz[(b*M_ + i)*3 + 0] = px[ix];
        out_xyz[(b*M_ + i)*3 + 1] = py[ix];
        out_xyz[(b*M_ + i)*3 + 2] = pz[ix];
    }
}

// ---------------- Ball query ----------------
// One block per center, single pass: collect candidates (d<=r^2) into LDS via
// atomic, track global argmin. Then rank candidates by (d, idx) lexicographic
// (== stable argsort ascending); slots >= count get the nearest index.
__global__ __launch_bounds__(256) void ballq_kernel(const float* __restrict__ xyz,
                                                    const int* __restrict__ fps_idx,
                                                    int* __restrict__ ball_idx) {
#pragma clang fp contract(off)
    __shared__ float cd[CAP];
    __shared__ int   ci[CAP];
    __shared__ int   cnt;
    __shared__ float rv[4];
    __shared__ int   ri[4];
    __shared__ int   slots[33];  // [0..31] ranked candidates, [32] global argmin
    int blk = blockIdx.x;
    int b = blk >> 10, m = blk & (M_ - 1);
    int t = threadIdx.x;
    if (t == 0) cnt = 0;
    __syncthreads();
    const float* xb = xyz + (size_t)b * N_ * 3;
    int cidx = fps_idx[b*M_ + m];
    float cx = xb[cidx*3+0], cy = xb[cidx*3+1], cz = xb[cidx*3+2];
    float bv = 3.4e38f; int bi = 0x7fffffff;
    for (int i = t; i < N_; i += 256) {
        float dx = xb[i*3+0] - cx, dy = xb[i*3+1] - cy, dz = xb[i*3+2] - cz;
        float t0 = dx*dx, t1 = dy*dy, t2 = dz*dz;
        float d = (t0 + t1) + t2;
        if (d < bv || (d == bv && i < bi)) { bv = d; bi = i; }
        if (d <= R2) {
            int p = atomicAdd(&cnt, 1);
            if (p < CAP) { cd[p] = d; ci[p] = i; }
        }
    }
    // global argmin reduce (needed when no candidate within radius)
    for (int off = 32; off >= 1; off >>= 1) {
        float ov = __shfl_xor(bv, off, 64);
        int   oi = __shfl_xor(bi, off, 64);
        if (ov < bv || (ov == bv && oi < bi)) { bv = ov; bi = oi; }
    }
    int w = t >> 6;
    if ((t & 63) == 0) { rv[w] = bv; ri[w] = bi; }
    __syncthreads();
    int n = cnt < CAP ? cnt : CAP;
    // rank each candidate; rank < 32 writes its output slot
    for (int j = t; j < n; j += 256) {
        float dj = cd[j]; int ij = ci[j];
        int rank = 0;
        for (int k = 0; k < n; k++) {
            float dk = cd[k]; int ik = ci[k];
            rank += (dk < dj) || (dk == dj && ik < ij);
        }
        if (rank < S_) slots[rank] = ij;
    }
    if (t == 0) {
        float v = rv[0]; int ix = ri[0];
        for (int j = 1; j < 4; j++)
            if (rv[j] < v || (rv[j] == v && ri[j] < ix)) { v = rv[j]; ix = ri[j]; }
        slots[32] = ix;
    }
    __syncthreads();
    if (t < S_) {
        int nearest = (n > 0) ? slots[0] : slots[32];
        int ix = (t < n) ? slots[t] : nearest;
        ball_idx[(size_t)(b*M_ + m)*S_ + t] = ix;
    }
}

// ---------------- MLP chain ----------------
// One block per center; whole chain in LDS. MODE: 0=stats L0, 1=stats L1,
// 2=stats L2, 3=final (normalize L2 + relu + max over samples -> out).
// stats layout: [sum0(64) sq0(64) sum1(64) sq1(64) sum2(128) sq2(128)]
// coef  layout: [a0(64) c0(64) a1(64) c1(64) a2(128) c2(128)], y_n = y*a + c
template<int MODE>
__global__ __launch_bounds__(256) void mlp_kernel(
    const float* __restrict__ xyz, const float* __restrict__ feat,
    const int* __restrict__ fps_idx, const int* __restrict__ ball_idx,
    const float* __restrict__ w0, const float* __restrict__ b0,
    const float* __restrict__ w1, const float* __restrict__ b1,
    const float* __restrict__ w2, const float* __restrict__ b2,
    const float* __restrict__ coef, float* __restrict__ stats,
    float* __restrict__ out_feat) {
    __shared__ float xs[S_*C0IN];
    __shared__ float y0s[S_*C0];
    __shared__ float y1s[S_*C1];
    __shared__ float red[256];
    __shared__ float red2[256];
    __shared__ int idxs[S_];
    int blk = blockIdx.x;
    int b = blk >> 10, m = blk & (M_ - 1);
    int t = threadIdx.x;
    const float* xb = xyz + (size_t)b * N_ * 3;
    int cidx = fps_idx[b*M_ + m];
    float cx = xb[cidx*3+0], cy = xb[cidx*3+1], cz = xb[cidx*3+2];
    if (t < S_) idxs[t] = ball_idx[(size_t)(b*M_ + m)*S_ + t];
    __syncthreads();
    // gather x = [grouped_xyz(3) | grouped_feat(64)]
    for (int i = t; i < S_*C0IN; i += 256) {
        int s = i / C0IN, c = i - s * C0IN;
        int p = idxs[s];
        float v;
        if (c == 0)      v = xb[p*3+0] - cx;
        else if (c == 1) v = xb[p*3+1] - cy;
        else if (c == 2) v = xb[p*3+2] - cz;
        else             v = feat[((size_t)b*N_ + p)*IN_ + (c - 3)];
        xs[i] = v;
    }
    __syncthreads();
    // ---- layer 0: 67 -> 64
    {
        float lsum = 0.f, lsq = 0.f;
        int d = t & 63;
        for (int o = t; o < S_*C0; o += 256) {
            int s = o >> 6;
            float acc = b0[d];
            const float* wr = w0 + d * C0IN;
            const float* xr = xs + s * C0IN;
            for (int c = 0; c < C0IN; c++) acc += xr[c] * wr[c];
            if (MODE == 0) { lsum += acc; lsq += acc * acc; }
            else {
                float v = acc * coef[d] + coef[64 + d];
                y0s[s*C0 + d] = v > 0.f ? v : 0.f;
            }
        }
        if (MODE == 0) {
            red[t] = lsum; red2[t] = lsq;
            __syncthreads();
            if (t < 64) {
                atomicAdd(&stats[t],      red[t]  + red[t+64]  + red[t+128]  + red[t+192]);
                atomicAdd(&stats[64 + t], red2[t] + red2[t+64] + red2[t+128] + red2[t+192]);
            }
            return;
        }
    }
    __syncthreads();
    // ---- layer 1: 64 -> 64
    {
        float lsum = 0.f, lsq = 0.f;
        int d = t & 63;
        for (int o = t; o < S_*C1; o += 256) {
            int s = o >> 6;
            float acc = b1[d];
            const float* wr = w1 + d * C0;
            const float* yr = y0s + s * C0;
            for (int c = 0; c < C0; c++) acc += yr[c] * wr[c];
            if (MODE == 1) { lsum += acc; lsq += acc * acc; }
            else {
                float v = acc * coef[128 + d] + coef[192 + d];
                y1s[s*C1 + d] = v > 0.f ? v : 0.f;
            }
        }
        if (MODE == 1) {
            red[t] = lsum; red2[t] = lsq;
            __syncthreads();
            if (t < 64) {
                atomicAdd(&stats[128 + t], red[t]  + red[t+64]  + red[t+128]  + red[t+192]);
                atomicAdd(&stats[192 + t], red2[t] + red2[t+64] + red2[t+128] + red2[t+192]);
            }
            return;
        }
    }
    __syncthreads();
    // ---- layer 2: 64 -> 128
    {
        int d = t & 127;
        float lsum = 0.f, lsq = 0.f, lmax = -3.4e38f;
        for (int o = t; o < S_*C2; o += 256) {
            int s = o >> 7;
            float acc = b2[d];
            const float* wr = w2 + d * C1;
            const float* yr = y1s + s * C1;
            for (int c = 0; c < C1; c++) acc += yr[c] * wr[c];
            if (MODE == 2) { lsum += acc; lsq += acc * acc; }
            else {
                float v = acc * coef[256 + d] + coef[384 + d];
                v = v > 0.f ? v : 0.f;
                lmax = v > lmax ? v : lmax;
            }
        }
        if (MODE == 2) {
            red[t] = lsum; red2[t] = lsq;
            __syncthreads();
            if (t < 128) {
                atomicAdd(&stats[256 + t], red[t]  + red[t+128]);
                atomicAdd(&stats[384 + t], red2[t] + red2[t+128]);
            }
            return;
        }
        red[t] = lmax;
        __syncthreads();
        if (t < 128) {
            float v = red[t] > red[t+128] ? red[t] : red[t+128];
            out_feat[(size_t)(b*M_ + m)*C2 + t] = v;
        }
    }
}

// mean/var -> affine coefs: y_n = y*a + c
__global__ void finalize_kernel(const float* __restrict__ stats,
                                const float* __restrict__ gamma,
                                const float* __restrict__ beta,
                                float* __restrict__ coef, int C) {
    int t = threadIdx.x;
    if (t < C) {
        float inv_n = 1.0f / (float)NTOT;
        float mean = stats[t] * inv_n;
        float var = stats[C + t] * inv_n - mean * mean;
        float rstd = 1.0f / sqrtf(var + 1e-5f);
        float a = gamma[t] * rstd;
        coef[t] = a;
        coef[C + t] = beta[t] - mean * a;
    }
}

extern "C" void kernel_launch(void* const* d_in, const int* in_sizes, int n_in,
                              void* d_out, int out_size, void* d_ws, size_t ws_size,
                              hipStream_t stream) {
    const float* xyz  = (const float*)d_in[0];
    const float* feat = (const float*)d_in[1];
    const float* w0 = (const float*)d_in[2];  const float* b0 = (const float*)d_in[3];
    const float* g0 = (const float*)d_in[4];  const float* be0 = (const float*)d_in[5];
    const float* w1 = (const float*)d_in[6];  const float* b1 = (const float*)d_in[7];
    const float* g1 = (const float*)d_in[8];  const float* be1 = (const float*)d_in[9];
    const float* w2 = (const float*)d_in[10]; const float* b2 = (const float*)d_in[11];
    const float* g2 = (const float*)d_in[12]; const float* be2 = (const float*)d_in[13];
    float* out_xyz  = (float*)d_out;
    float* out_feat = out_xyz + B_*M_*3;

    int* fps_i  = (int*)d_ws;                                   // 16384 ints
    int* ball_i = (int*)((char*)d_ws + 65536);                  // 524288 ints
    float* stats = (float*)((char*)d_ws + 65536 + 2097152);     // 512 floats
    float* coef  = stats + 512;                                 // 512 floats

    hipMemsetAsync(stats, 0, 512 * sizeof(float), stream);
    fps_kernel<<<B_, FPS_T, 0, stream>>>(xyz, fps_i, out_xyz);
    ballq_kernel<<<B_*M_, 256, 0, stream>>>(xyz, fps_i, ball_i);
    mlp_kernel<0><<<B_*M_, 256, 0, stream>>>(xyz, feat, fps_i, ball_i,
        w0, b0, w1, b1, w2, b2, coef, stats, out_feat);
    finalize_kernel<<<1, 128, 0, stream>>>(stats, g0, be0, coef, 64);
    mlp_kernel<1><<<B_*M_, 256, 0, stream>>>(xyz, feat, fps_i, ball_i,
        w0, b0, w1, b1, w2, b2, coef, stats, out_feat);
    finalize_kernel<<<1, 128, 0, stream>>>(stats + 128, g1, be1, coef + 128, 64);
    mlp_kernel<2><<<B_*M_, 256, 0, stream>>>(xyz, feat, fps_i, ball_i,
        w0, b0, w1, b1, w2, b2, coef, stats, out_feat);
    finalize_kernel<<<1, 128, 0, stream>>>(stats + 256, g2, be2, coef + 256, 128);
    mlp_kernel<3><<<B_*M_, 256, 0, stream>>>(xyz, feat, fps_i, ball_i,
        w0, b0, w1, b1, w2, b2, coef, stats, out_feat);
}